// Round 3
// baseline (271.071 us; speedup 1.0000x reference)
//
#include <hip/hip_runtime.h>
#include <math.h>

// ---------------- constant tables ----------------
__constant__ int G_ORD[17] = {0,1,2,3,4,5,6, 10,11,12,13, 7,8,9, 14,15, 16};
__constant__ int G_WA[17]  = {0,2,4,6,1,3,5, 1,3,5,7, 0,4,2, 2,6, 0};
__constant__ int G_WB[17]  = {1,3,5,7,2,4,6, 0,2,4,6, 2,6,4, 0,4, 4};
__constant__ int CDESC[10][3] = {{0,0,1},{0,2,3},{0,4,5},{0,6,7},{0,1,2},{0,3,4},{0,5,6},
                                 {1,0,1},{1,2,3},{1,1,2}};
__constant__ int PDESC[6][2] = {{0,0},{0,1},{0,2},{0,3},{1,0},{1,1}};
__constant__ float2 PMAT[4][4] = {
  {{1.f,0.f},{0.f,0.f},{0.f,0.f},{1.f,0.f}},
  {{0.f,0.f},{1.f,0.f},{1.f,0.f},{0.f,0.f}},
  {{0.f,0.f},{0.f,-1.f},{0.f,1.f},{0.f,0.f}},
  {{1.f,0.f},{0.f,0.f},{0.f,0.f},{-1.f,0.f}}};

__device__ __forceinline__ float2 cmul(float2 a, float2 b){
  return make_float2(a.x*b.x - a.y*b.y, a.x*b.y + a.y*b.x);
}
__device__ __forceinline__ float2 cadd(float2 a, float2 b){
  return make_float2(a.x+b.x, a.y+b.y);
}

__device__ void u3m(float t, float p, float d, float2* u){
  float ct = cosf(0.5f*t), st = sinf(0.5f*t);
  u[0] = make_float2(ct, 0.f);
  u[1] = make_float2(-cosf(d)*st, -sinf(d)*st);
  u[2] = make_float2(cosf(p)*st,  sinf(p)*st);
  u[3] = make_float2(cosf(p+d)*ct, sinf(p+d)*ct);
}

__device__ void kron2(const float2* A, const float2* B, float2* M){
  #pragma unroll
  for (int ia=0; ia<2; ia++)
    #pragma unroll
    for (int ib=0; ib<2; ib++)
      #pragma unroll
      for (int ja=0; ja<2; ja++)
        #pragma unroll
        for (int jb=0; jb<2; jb++)
          M[(ia*2+ib)*4 + (ja*2+jb)] = cmul(A[ia*2+ja], B[ib*2+jb]);
}

__device__ void mul44(const float2* A, const float2* B, float2* C){
  #pragma unroll
  for (int r=0;r<4;r++)
    #pragma unroll
    for (int c=0;c<4;c++){
      float2 s = make_float2(0.f,0.f);
      #pragma unroll
      for (int k=0;k<4;k++) s = cadd(s, cmul(A[r*4+k], B[k*4+c]));
      C[r*4+c] = s;
    }
}

__device__ void rotword(float phi, int qa, int qb, float2* R){
  float ch = cosf(0.5f*phi), sh = sinf(0.5f*phi);
  float2 W[16];
  kron2(PMAT[qa], PMAT[qb], W);
  #pragma unroll
  for (int i=0;i<16;i++) R[i] = make_float2(sh*W[i].y, -sh*W[i].x);
  #pragma unroll
  for (int d=0;d<4;d++) R[d*4+d].x += ch;
}

// ---------------- kernel 1: gates (redundant per block, in LDS) + U columns ----------------
// 256 blocks x 64 threads; block b evolves identity column b through the 17 fused gates.
__global__ __launch_bounds__(64) void build_u_kernel(
    const float* __restrict__ conv, const float* __restrict__ pool,
    const float* __restrict__ last, float2* __restrict__ U){
  __shared__ float2 gl[17][16];
  __shared__ float2 st[256];
  int t = threadIdx.x, col = blockIdx.x;
  // --- phase A: 17 lanes each build one fused 4x4 gate ---
  {
    float2 M[16], T[16], R[16];
    if (t < 10){
      int layer = CDESC[t][0], ra = CDESC[t][1], rb = CDESC[t][2];
      const float* cw = conv + layer*120;
      int bA = ra*15, bB = rb*15;
      float2 A1[4], B1[4], A2[4], B2[4], K[16];
      u3m(cw[bA+0], cw[bA+1], cw[bA+2], A1);
      u3m(cw[bB+3], cw[bB+4], cw[bB+5], B1);
      kron2(A1, B1, M);
      rotword(cw[bA+6], 3, 3, R); mul44(R, M, T);   // ZZ
      rotword(cw[bA+7], 2, 2, R); mul44(R, T, M);   // YY
      rotword(cw[bA+8], 1, 1, R); mul44(R, M, T);   // XX
      u3m(cw[bA+9],  cw[bA+10], cw[bA+11], A2);
      u3m(cw[bB+12], cw[bB+13], cw[bB+14], B2);
      kron2(A2, B2, K); mul44(K, T, M);
    } else if (t < 16){
      int layer = PDESC[t-10][0], h = PDESC[t-10][1];
      const float* pw = pool + layer*12 + h*3;
      float2 u[4];
      u3m(pw[0], pw[1], pw[2], u);
      #pragma unroll
      for (int i=0;i<16;i++) M[i] = make_float2(0.f,0.f);
      M[0]  = make_float2(1.f,0.f);
      M[5]  = make_float2(1.f,0.f);
      M[10] = u[0]; M[11] = u[1]; M[14] = u[2]; M[15] = u[3];
    } else if (t == 16){
      #pragma unroll
      for (int i=0;i<16;i++) M[i] = make_float2((i%5==0)?1.f:0.f, 0.f);
      for (int k=0;k<15;k++){
        int w = k+1;
        rotword(last[k], w>>2, w&3, R);
        mul44(R, M, T);
        #pragma unroll
        for (int i=0;i<16;i++) M[i] = T[i];
      }
    }
    if (t < 17){
      #pragma unroll
      for (int i=0;i<16;i++) gl[t][i] = M[i];
    }
  }
  // --- phase B: evolve identity column ---
  #pragma unroll
  for (int k=t; k<256; k+=64) st[k] = make_float2(k==col ? 1.f : 0.f, 0.f);
  __syncthreads();
  for (int g=0; g<17; g++){
    int slot = G_ORD[g];
    float2 m[16];
    #pragma unroll
    for (int i=0;i<16;i++) m[i] = gl[slot][i];
    int pa = 7 - G_WA[g], pb = 7 - G_WB[g];
    int plo = pa < pb ? pa : pb, phi_ = pa < pb ? pb : pa;
    int mm = t;
    int t1   = ((mm >> plo) << (plo+1)) | (mm & ((1<<plo)-1));
    int base = ((t1 >> phi_) << (phi_+1)) | (t1 & ((1<<phi_)-1));
    int ba = 1<<pa, bb = 1<<pb;
    int i0 = base, i1 = base|bb, i2 = base|ba, i3 = base|ba|bb;
    float2 s0 = st[i0], s1 = st[i1], s2 = st[i2], s3 = st[i3];
    float2 n0 = cadd(cadd(cmul(m[0], s0), cmul(m[1], s1)), cadd(cmul(m[2], s2), cmul(m[3], s3)));
    float2 n1 = cadd(cadd(cmul(m[4], s0), cmul(m[5], s1)), cadd(cmul(m[6], s2), cmul(m[7], s3)));
    float2 n2 = cadd(cadd(cmul(m[8], s0), cmul(m[9], s1)), cadd(cmul(m[10],s2), cmul(m[11],s3)));
    float2 n3 = cadd(cadd(cmul(m[12],s0), cmul(m[13],s1)), cadd(cmul(m[14],s2), cmul(m[15],s3)));
    st[i0] = n0; st[i1] = n1; st[i2] = n2; st[i3] = n3;
    __syncthreads();
  }
  #pragma unroll
  for (int k=t; k<256; k+=64) U[k*256 + col] = st[k];
}

// ---------------- kernel 2: A[i][j] = sum_k sgn_k Re(conj(U_ki) U_kj) ----------------
// 256 blocks (row i) x 256 threads (col j).
__global__ __launch_bounds__(256) void build_a_kernel(
    const float2* __restrict__ U, float* __restrict__ A){
  int j = threadIdx.x, i = blockIdx.x;
  float a0 = 0.f;
  #pragma unroll 8
  for (int k=0; k<256; k++){
    float2 uj = U[k*256 + j];
    float2 ui = U[k*256 + i];
    float sgn = (k < 128) ? 1.f : -1.f;   // qubit0 = bit7 (MSB), Z eigenvalue
    a0 += sgn*(ui.x*uj.x + ui.y*uj.y);
  }
  A[i*256 + j] = a0;
}

// ---------------- kernel 3: feats = tanh(x @ fc_w^T + fc_b) ----------------
// 512 blocks x 256 threads; 16 rows/block (wave wv -> rows r0+wv*4..+3).
__global__ __launch_bounds__(256) void feats_kernel(
    const float* __restrict__ x, const float* __restrict__ fcw,
    const float* __restrict__ fcb, float* __restrict__ feats){
  __shared__ float red[128*68];
  int t = threadIdx.x, lane = t & 63, wv = t >> 6;
  int r0 = blockIdx.x * 16;
  int rw = r0 + wv*4;
  const float4* x4 = (const float4*)x;
  const float4* w4 = (const float4*)fcw;
  float acc[4][8];
  #pragma unroll
  for (int r=0;r<4;r++)
    #pragma unroll
    for (int o=0;o<8;o++) acc[r][o] = 0.f;
  #pragma unroll 2
  for (int p=0; p<12; p++){
    float4 wf[8];
    #pragma unroll
    for (int o=0;o<8;o++) wf[o] = w4[o*768 + p*64 + lane];
    #pragma unroll
    for (int r=0;r<4;r++){
      float4 xv = x4[(size_t)(rw+r)*768 + p*64 + lane];
      #pragma unroll
      for (int o=0;o<8;o++){
        acc[r][o] += xv.x*wf[o].x + xv.y*wf[o].y + xv.z*wf[o].z + xv.w*wf[o].w;
      }
    }
  }
  #pragma unroll
  for (int r=0;r<4;r++)
    #pragma unroll
    for (int o=0;o<8;o++)
      red[((wv*4+r)*8 + o)*68 + lane] = acc[r][o];
  __syncthreads();
  if (t < 128){
    const float4* rp = (const float4*)(red + t*68);
    float4 s4 = make_float4(0.f,0.f,0.f,0.f);
    #pragma unroll
    for (int i=0;i<16;i++){
      float4 v = rp[i];
      s4.x += v.x; s4.y += v.y; s4.z += v.z; s4.w += v.w;
    }
    float s = s4.x + s4.y + s4.z + s4.w + fcb[t & 7];
    feats[(r0 + (t>>3))*8 + (t&7)] = tanhf(s);
  }
}

// ---------------- kernel 4: q = psi^T A psi ; logits ----------------
// 512 blocks x 128 threads (2 waves); 16 rows/block, 8 rows/thread, lane jb = 4 cols.
// LDS: As 32KB (A k-chunk) + ps 16KB (psi rows). 2 blocks/CU -> 4 waves/CU.
// Per-CU LDS cost: 256k x 4 waves x (12 As + 8 ps) cyc ~ 20.5k cyc = 8.5us; VALU 6.8us.
__global__ __launch_bounds__(128) void qform_kernel(
    const float* __restrict__ Ag, const float* __restrict__ feats,
    const float* __restrict__ outw, const float* __restrict__ outb,
    float* __restrict__ out){
  __shared__ float As[32*256];   // 32 KB
  __shared__ float ps[16*256];   // 16 KB
  __shared__ float qv[16];
  int t = threadIdx.x;
  int r0 = blockIdx.x * 16;
  // phase 0: build psi rows in LDS. thread t -> (row=t>>3, i1 = (t&7) and (t&7)+8)
  {
    int row = t >> 3, sub = t & 7;
    const float* f = feats + (r0 + row)*8;
    float c[8], s[8];
    #pragma unroll
    for (int w=0; w<8; w++){
      float a = 0.5f*f[w];
      __sincosf(a, &s[w], &c[w]);
    }
    float hr = (sub&4 ? s[1]:c[1]) * (sub&2 ? s[2]:c[2]) * (sub&1 ? s[3]:c[3]);
    float Hv_a = c[0]*hr, Hv_b = s[0]*hr;
    float l2[2], l4[4], l8[8], L[16];
    l2[0]=c[4]; l2[1]=s[4];
    #pragma unroll
    for (int a=0;a<2;a++){ l4[a*2]=l2[a]*c[5]; l4[a*2+1]=l2[a]*s[5]; }
    #pragma unroll
    for (int a=0;a<4;a++){ l8[a*2]=l4[a]*c[6]; l8[a*2+1]=l4[a]*s[6]; }
    #pragma unroll
    for (int a=0;a<8;a++){ L[a*2]=l8[a]*c[7]; L[a*2+1]=l8[a]*s[7]; }
    float4* da = (float4*)(ps + row*256 + sub*16);
    float4* db = (float4*)(ps + row*256 + (sub+8)*16);
    #pragma unroll
    for (int qd=0; qd<4; qd++){
      da[qd] = make_float4(Hv_a*L[qd*4+0], Hv_a*L[qd*4+1], Hv_a*L[qd*4+2], Hv_a*L[qd*4+3]);
      db[qd] = make_float4(Hv_b*L[qd*4+0], Hv_b*L[qd*4+1], Hv_b*L[qd*4+2], Hv_b*L[qd*4+3]);
    }
  }
  int wv = t >> 6, jb = t & 63;
  const float4* As4 = (const float4*)As;
  const float4* ps4 = (const float4*)ps;
  const float4* Ag4 = (const float4*)Ag;
  float4 acc4[8];
  #pragma unroll
  for (int r=0;r<8;r++) acc4[r] = make_float4(0.f,0.f,0.f,0.f);
  for (int chunk=0; chunk<8; chunk++){
    __syncthreads();   // orders phase-0 / previous compute before restaging
    #pragma unroll
    for (int pass=0; pass<16; pass++){
      int kk = pass*2 + wv;
      As4[0]; // no-op
      *(float4*)(As + kk*256 + jb*4) = Ag4[(chunk*32 + kk)*64 + jb];
    }
    __syncthreads();
    #pragma unroll 2
    for (int kq=0; kq<8; kq++){
      float4 av0 = As4[(kq*4+0)*64 + jb];
      float4 av1 = As4[(kq*4+1)*64 + jb];
      float4 av2 = As4[(kq*4+2)*64 + jb];
      float4 av3 = As4[(kq*4+3)*64 + jb];
      #pragma unroll
      for (int r=0; r<8; r++){
        float4 pv = ps4[(wv*8+r)*64 + chunk*8 + kq];   // wave-uniform broadcast
        acc4[r].x += pv.x*av0.x + pv.y*av1.x + pv.z*av2.x + pv.w*av3.x;
        acc4[r].y += pv.x*av0.y + pv.y*av1.y + pv.z*av2.y + pv.w*av3.y;
        acc4[r].z += pv.x*av0.z + pv.y*av1.z + pv.z*av2.z + pv.w*av3.z;
        acc4[r].w += pv.x*av0.w + pv.y*av1.w + pv.z*av2.w + pv.w*av3.w;
      }
    }
  }
  // epilogue: q_r = sum_j psi[row][j]*(A psi)[j]; butterfly over 64 lanes
  #pragma unroll
  for (int r=0; r<8; r++){
    float4 psv = ps4[(wv*8+r)*64 + jb];
    float pr = acc4[r].x*psv.x + acc4[r].y*psv.y + acc4[r].z*psv.z + acc4[r].w*psv.w;
    #pragma unroll
    for (int m=1; m<64; m<<=1) pr += __shfl_xor(pr, m, 64);
    if (jb == 0) qv[wv*8 + r] = pr;
  }
  __syncthreads();
  for (int u=t; u<160; u+=128){
    int row = u/10, c = u - row*10;
    out[(r0 + row)*10 + c] = qv[row]*outw[c] + outb[c];
  }
}

// ---------------- launch ----------------
extern "C" void kernel_launch(void* const* d_in, const int* in_sizes, int n_in,
                              void* d_out, int out_size, void* d_ws, size_t ws_size,
                              hipStream_t stream) {
  const float* x    = (const float*)d_in[0];
  const float* fcw  = (const float*)d_in[1];
  const float* fcb  = (const float*)d_in[2];
  const float* conv = (const float*)d_in[3];
  const float* pool = (const float*)d_in[4];
  const float* last = (const float*)d_in[5];
  const float* outw = (const float*)d_in[6];
  const float* outb = (const float*)d_in[7];
  float* out = (float*)d_out;

  float* ws = (float*)d_ws;
  float2* U     = (float2*)ws;                      // 256*256 complex = 131072 floats
  float*  Am    = ws + 131072;                      // 65536 floats
  float*  feats = Am + 65536;                       // 8192*8 = 65536 floats

  build_u_kernel<<<256, 64, 0, stream>>>(conv, pool, last, U);
  build_a_kernel<<<256, 256, 0, stream>>>(U, Am);
  feats_kernel<<<512, 256, 0, stream>>>(x, fcw, fcb, feats);
  qform_kernel<<<512, 128, 0, stream>>>(Am, feats, outw, outb, out);
}

// Round 4
// 244.725 us; speedup vs baseline: 1.1077x; 1.1077x over previous
//
#include <hip/hip_runtime.h>
#include <math.h>

// ---------------- constant tables ----------------
__constant__ int G_ORD[17] = {0,1,2,3,4,5,6, 10,11,12,13, 7,8,9, 14,15, 16};
__constant__ int G_WA[17]  = {0,2,4,6,1,3,5, 1,3,5,7, 0,4,2, 2,6, 0};
__constant__ int G_WB[17]  = {1,3,5,7,2,4,6, 0,2,4,6, 2,6,4, 0,4, 4};
__constant__ int CDESC[10][3] = {{0,0,1},{0,2,3},{0,4,5},{0,6,7},{0,1,2},{0,3,4},{0,5,6},
                                 {1,0,1},{1,2,3},{1,1,2}};
__constant__ int PDESC[6][2] = {{0,0},{0,1},{0,2},{0,3},{1,0},{1,1}};
__constant__ float2 PMAT[4][4] = {
  {{1.f,0.f},{0.f,0.f},{0.f,0.f},{1.f,0.f}},
  {{0.f,0.f},{1.f,0.f},{1.f,0.f},{0.f,0.f}},
  {{0.f,0.f},{0.f,-1.f},{0.f,1.f},{0.f,0.f}},
  {{1.f,0.f},{0.f,0.f},{0.f,0.f},{-1.f,0.f}}};

__device__ __forceinline__ float2 cmul(float2 a, float2 b){
  return make_float2(a.x*b.x - a.y*b.y, a.x*b.y + a.y*b.x);
}
__device__ __forceinline__ float2 cadd(float2 a, float2 b){
  return make_float2(a.x+b.x, a.y+b.y);
}

__device__ void u3m(float t, float p, float d, float2* u){
  float ct = cosf(0.5f*t), st = sinf(0.5f*t);
  u[0] = make_float2(ct, 0.f);
  u[1] = make_float2(-cosf(d)*st, -sinf(d)*st);
  u[2] = make_float2(cosf(p)*st,  sinf(p)*st);
  u[3] = make_float2(cosf(p+d)*ct, sinf(p+d)*ct);
}

__device__ void kron2(const float2* A, const float2* B, float2* M){
  #pragma unroll
  for (int ia=0; ia<2; ia++)
    #pragma unroll
    for (int ib=0; ib<2; ib++)
      #pragma unroll
      for (int ja=0; ja<2; ja++)
        #pragma unroll
        for (int jb=0; jb<2; jb++)
          M[(ia*2+ib)*4 + (ja*2+jb)] = cmul(A[ia*2+ja], B[ib*2+jb]);
}

__device__ void mul44(const float2* A, const float2* B, float2* C){
  #pragma unroll
  for (int r=0;r<4;r++)
    #pragma unroll
    for (int c=0;c<4;c++){
      float2 s = make_float2(0.f,0.f);
      #pragma unroll
      for (int k=0;k<4;k++) s = cadd(s, cmul(A[r*4+k], B[k*4+c]));
      C[r*4+c] = s;
    }
}

__device__ void rotword(float phi, int qa, int qb, float2* R){
  float ch = cosf(0.5f*phi), sh = sinf(0.5f*phi);
  float2 W[16];
  kron2(PMAT[qa], PMAT[qb], W);
  #pragma unroll
  for (int i=0;i<16;i++) R[i] = make_float2(sh*W[i].y, -sh*W[i].x);
  #pragma unroll
  for (int d=0;d<4;d++) R[d*4+d].x += ch;
}

// ---------------- kernel 1: gates (redundant per block, in LDS) + U columns ----------------
__global__ __launch_bounds__(64) void build_u_kernel(
    const float* __restrict__ conv, const float* __restrict__ pool,
    const float* __restrict__ last, float2* __restrict__ U){
  __shared__ float2 gl[17][16];
  __shared__ float2 st[256];
  int t = threadIdx.x, col = blockIdx.x;
  {
    float2 M[16], T[16], R[16];
    if (t < 10){
      int layer = CDESC[t][0], ra = CDESC[t][1], rb = CDESC[t][2];
      const float* cw = conv + layer*120;
      int bA = ra*15, bB = rb*15;
      float2 A1[4], B1[4], A2[4], B2[4], K[16];
      u3m(cw[bA+0], cw[bA+1], cw[bA+2], A1);
      u3m(cw[bB+3], cw[bB+4], cw[bB+5], B1);
      kron2(A1, B1, M);
      rotword(cw[bA+6], 3, 3, R); mul44(R, M, T);   // ZZ
      rotword(cw[bA+7], 2, 2, R); mul44(R, T, M);   // YY
      rotword(cw[bA+8], 1, 1, R); mul44(R, M, T);   // XX
      u3m(cw[bA+9],  cw[bA+10], cw[bA+11], A2);
      u3m(cw[bB+12], cw[bB+13], cw[bB+14], B2);
      kron2(A2, B2, K); mul44(K, T, M);
    } else if (t < 16){
      int layer = PDESC[t-10][0], h = PDESC[t-10][1];
      const float* pw = pool + layer*12 + h*3;
      float2 u[4];
      u3m(pw[0], pw[1], pw[2], u);
      #pragma unroll
      for (int i=0;i<16;i++) M[i] = make_float2(0.f,0.f);
      M[0]  = make_float2(1.f,0.f);
      M[5]  = make_float2(1.f,0.f);
      M[10] = u[0]; M[11] = u[1]; M[14] = u[2]; M[15] = u[3];
    } else if (t == 16){
      #pragma unroll
      for (int i=0;i<16;i++) M[i] = make_float2((i%5==0)?1.f:0.f, 0.f);
      for (int k=0;k<15;k++){
        int w = k+1;
        rotword(last[k], w>>2, w&3, R);
        mul44(R, M, T);
        #pragma unroll
        for (int i=0;i<16;i++) M[i] = T[i];
      }
    }
    if (t < 17){
      #pragma unroll
      for (int i=0;i<16;i++) gl[t][i] = M[i];
    }
  }
  #pragma unroll
  for (int k=t; k<256; k+=64) st[k] = make_float2(k==col ? 1.f : 0.f, 0.f);
  __syncthreads();
  for (int g=0; g<17; g++){
    int slot = G_ORD[g];
    float2 m[16];
    #pragma unroll
    for (int i=0;i<16;i++) m[i] = gl[slot][i];
    int pa = 7 - G_WA[g], pb = 7 - G_WB[g];
    int plo = pa < pb ? pa : pb, phi_ = pa < pb ? pb : pa;
    int mm = t;
    int t1   = ((mm >> plo) << (plo+1)) | (mm & ((1<<plo)-1));
    int base = ((t1 >> phi_) << (phi_+1)) | (t1 & ((1<<phi_)-1));
    int ba = 1<<pa, bb = 1<<pb;
    int i0 = base, i1 = base|bb, i2 = base|ba, i3 = base|ba|bb;
    float2 s0 = st[i0], s1 = st[i1], s2 = st[i2], s3 = st[i3];
    float2 n0 = cadd(cadd(cmul(m[0], s0), cmul(m[1], s1)), cadd(cmul(m[2], s2), cmul(m[3], s3)));
    float2 n1 = cadd(cadd(cmul(m[4], s0), cmul(m[5], s1)), cadd(cmul(m[6], s2), cmul(m[7], s3)));
    float2 n2 = cadd(cadd(cmul(m[8], s0), cmul(m[9], s1)), cadd(cmul(m[10],s2), cmul(m[11],s3)));
    float2 n3 = cadd(cadd(cmul(m[12],s0), cmul(m[13],s1)), cadd(cmul(m[14],s2), cmul(m[15],s3)));
    st[i0] = n0; st[i1] = n1; st[i2] = n2; st[i3] = n3;
    __syncthreads();
  }
  #pragma unroll
  for (int k=t; k<256; k+=64) U[k*256 + col] = st[k];
}

// ---------------- kernel 2: A[i][j] = sum_k sgn_k Re(conj(U_ki) U_kj) ----------------
// 128 blocks x 2 rows, 256 threads (col j). uj coalesced, ui wave-uniform broadcast.
__global__ __launch_bounds__(256) void build_a_kernel(
    const float2* __restrict__ U, float* __restrict__ A){
  int j = threadIdx.x, i0 = blockIdx.x*2;
  float a0=0.f, a1=0.f;
  #pragma unroll 8
  for (int k=0; k<256; k++){
    float2 uj = U[k*256 + j];
    float2 u0 = U[k*256 + i0+0];
    float2 u1 = U[k*256 + i0+1];
    float sgn = (k < 128) ? 1.f : -1.f;   // qubit0 = bit7 (MSB), Z eigenvalue
    a0 += sgn*(u0.x*uj.x + u0.y*uj.y);
    a1 += sgn*(u1.x*uj.x + u1.y*uj.y);
  }
  A[(i0+0)*256 + j] = a0;
  A[(i0+1)*256 + j] = a1;
}

// ---------------- kernel 3: fused feats(tanh GEMM) + psi + q=psi^T A psi + logits ----------
// 512 blocks x 256 threads; 16 rows/block. Wave wv owns rows r0+wv*4..+3 end-to-end.
// LDS union: feats-reduce scratch (128x68=34.8KB) dies before qform As(32KB)+ps(16KB).
__global__ __launch_bounds__(256) void main_kernel(
    const float* __restrict__ x, const float* __restrict__ fcw,
    const float* __restrict__ fcb, const float* __restrict__ Ag,
    const float* __restrict__ outw, const float* __restrict__ outb,
    float* __restrict__ out){
  __shared__ float lds[12288];        // 48 KB union
  __shared__ float flds[128];         // 16 rows x 8 feats
  float* red = lds;                   // phase F/R: 128 x 68
  float* As  = lds;                   // phase Q: 32 x 256
  float* ps  = lds + 8192;            // phase Q: 16 x 256
  int t = threadIdx.x, lane = t & 63, wv = t >> 6, jb = lane;
  int r0 = blockIdx.x * 16;
  // ---- phase F: per-wave GEMM over k=3072 (12 passes of float4) ----
  {
    int rw = r0 + wv*4;
    const float4* x4 = (const float4*)x;
    const float4* w4 = (const float4*)fcw;
    float acc[4][8];
    #pragma unroll
    for (int r=0;r<4;r++)
      #pragma unroll
      for (int o=0;o<8;o++) acc[r][o] = 0.f;
    #pragma unroll 2
    for (int p=0; p<12; p++){
      float4 wf[8];
      #pragma unroll
      for (int o=0;o<8;o++) wf[o] = w4[o*768 + p*64 + lane];
      #pragma unroll
      for (int r=0;r<4;r++){
        float4 xv = x4[(size_t)(rw+r)*768 + p*64 + lane];
        #pragma unroll
        for (int o=0;o<8;o++){
          acc[r][o] += xv.x*wf[o].x + xv.y*wf[o].y + xv.z*wf[o].z + xv.w*wf[o].w;
        }
      }
    }
    #pragma unroll
    for (int r=0;r<4;r++)
      #pragma unroll
      for (int o=0;o<8;o++)
        red[((wv*4+r)*8 + o)*68 + lane] = acc[r][o];
  }
  __syncthreads();
  // ---- phase R: LDS-transpose reduce + tanh -> flds ----
  if (t < 128){
    const float4* rp = (const float4*)(red + t*68);
    float4 s4 = make_float4(0.f,0.f,0.f,0.f);
    #pragma unroll
    for (int i=0;i<16;i++){
      float4 v = rp[i];
      s4.x += v.x; s4.y += v.y; s4.z += v.z; s4.w += v.w;
    }
    flds[t] = tanhf(s4.x + s4.y + s4.z + s4.w + fcb[t & 7]);
  }
  __syncthreads();
  // ---- phase P: build psi rows in ps (red still aliased but dead after next sync) ----
  float psi_local[16];  // not used; placeholder removed by compiler
  {
    int row = t >> 4, i1 = t & 15;
    const float* f = flds + row*8;
    float c[8], s[8];
    #pragma unroll
    for (int w=0; w<8; w++){
      float a = 0.5f*f[w];
      __sincosf(a, &s[w], &c[w]);
    }
    float Hv = (i1&8 ? s[0]:c[0]) * (i1&4 ? s[1]:c[1])
             * (i1&2 ? s[2]:c[2]) * (i1&1 ? s[3]:c[3]);
    float l2[2], l4[4], l8[8], L[16];
    l2[0]=c[4]; l2[1]=s[4];
    #pragma unroll
    for (int a=0;a<2;a++){ l4[a*2]=l2[a]*c[5]; l4[a*2+1]=l2[a]*s[5]; }
    #pragma unroll
    for (int a=0;a<4;a++){ l8[a*2]=l4[a]*c[6]; l8[a*2+1]=l4[a]*s[6]; }
    #pragma unroll
    for (int a=0;a<8;a++){ L[a*2]=l8[a]*c[7]; L[a*2+1]=l8[a]*s[7]; }
    #pragma unroll
    for (int j=0;j<16;j++) psi_local[j] = Hv*L[j];
  }
  // ps overlaps the tail of red: wait until all phase-R reads done, then write.
  __syncthreads();
  {
    int row = t >> 4, i1 = t & 15;
    float4* dst = (float4*)(ps + row*256 + i1*16);
    #pragma unroll
    for (int qd=0; qd<4; qd++)
      dst[qd] = make_float4(psi_local[qd*4+0], psi_local[qd*4+1],
                            psi_local[qd*4+2], psi_local[qd*4+3]);
  }
  // ---- phase Q: q = psi^T A psi over 8 chunks of 32 k-rows ----
  const float4* As4 = (const float4*)As;
  const float4* ps4 = (const float4*)ps;
  const float4* Ag4 = (const float4*)Ag;
  float4 acc4[4];
  #pragma unroll
  for (int r=0;r<4;r++) acc4[r] = make_float4(0.f,0.f,0.f,0.f);
  for (int chunk=0; chunk<8; chunk++){
    __syncthreads();   // orders ps writes (first iter) / prior compute before restage
    #pragma unroll
    for (int pass=0; pass<8; pass++){
      int kk = pass*4 + wv;
      *(float4*)(As + kk*256 + jb*4) = Ag4[(chunk*32 + kk)*64 + jb];
    }
    __syncthreads();
    #pragma unroll
    for (int kq=0; kq<8; kq++){
      float4 av0 = As4[(kq*4+0)*64 + jb];
      float4 av1 = As4[(kq*4+1)*64 + jb];
      float4 av2 = As4[(kq*4+2)*64 + jb];
      float4 av3 = As4[(kq*4+3)*64 + jb];
      #pragma unroll
      for (int r=0; r<4; r++){
        float4 pv = ps4[(wv*4+r)*64 + chunk*8 + kq];   // wave-uniform broadcast
        acc4[r].x += pv.x*av0.x + pv.y*av1.x + pv.z*av2.x + pv.w*av3.x;
        acc4[r].y += pv.x*av0.y + pv.y*av1.y + pv.z*av2.y + pv.w*av3.y;
        acc4[r].z += pv.x*av0.z + pv.y*av1.z + pv.z*av2.z + pv.w*av3.z;
        acc4[r].w += pv.x*av0.w + pv.y*av1.w + pv.z*av2.w + pv.w*av3.w;
      }
    }
  }
  // ---- epilogue: q_r = psi . (A psi), butterfly over 64 lanes, 40-lane store ----
  float p[4];
  #pragma unroll
  for (int r=0; r<4; r++){
    float4 psv = ps4[(wv*4+r)*64 + jb];
    float pr = acc4[r].x*psv.x + acc4[r].y*psv.y + acc4[r].z*psv.z + acc4[r].w*psv.w;
    #pragma unroll
    for (int m=1; m<64; m<<=1) pr += __shfl_xor(pr, m, 64);
    p[r] = pr;
  }
  if (jb < 40){
    int ridx = jb / 10, c = jb - ridx*10;
    float q = (ridx==0) ? p[0] : (ridx==1) ? p[1] : (ridx==2) ? p[2] : p[3];
    out[(r0 + wv*4 + ridx)*10 + c] = q*outw[c] + outb[c];
  }
}

// ---------------- launch ----------------
extern "C" void kernel_launch(void* const* d_in, const int* in_sizes, int n_in,
                              void* d_out, int out_size, void* d_ws, size_t ws_size,
                              hipStream_t stream) {
  const float* x    = (const float*)d_in[0];
  const float* fcw  = (const float*)d_in[1];
  const float* fcb  = (const float*)d_in[2];
  const float* conv = (const float*)d_in[3];
  const float* pool = (const float*)d_in[4];
  const float* last = (const float*)d_in[5];
  const float* outw = (const float*)d_in[6];
  const float* outb = (const float*)d_in[7];
  float* out = (float*)d_out;

  float* ws = (float*)d_ws;
  float2* U  = (float2*)ws;            // 256*256 complex = 131072 floats
  float*  Am = ws + 131072;            // 65536 floats

  build_u_kernel<<<256, 64, 0, stream>>>(conv, pool, last, U);
  build_a_kernel<<<128, 256, 0, stream>>>(U, Am);
  main_kernel<<<512, 256, 0, stream>>>(x, fcw, fcb, Am, outw, outb, out);
}